// Round 11
// baseline (174.561 us; speedup 1.0000x reference)
//
#include <hip/hip_runtime.h>
#include <math.h>

#define S_LEN 2048
#define NB 4
#define NH 8

typedef short bfrag8 __attribute__((ext_vector_type(8)));
typedef float f32x16 __attribute__((ext_vector_type(16)));
typedef float f32x4 __attribute__((ext_vector_type(4)));

#if __has_builtin(__builtin_amdgcn_exp2f)
#define EXP2(x) __builtin_amdgcn_exp2f(x)
#else
#define EXP2(x) exp2f(x)
#endif

__device__ __forceinline__ unsigned short f2bf(float x) {
  union { float f; unsigned u; } v; v.f = x;
  unsigned r = v.u + 0x7FFFu + ((v.u >> 16) & 1u);
  return (unsigned short)(r >> 16);
}

// Pack two fp32 -> one u32 of 2x bf16, round-half-up (2 ops/value, unbiased;
// differs from RNE only on exact-tie mantissas -> 1 ulp, measure-zero).
// NOTE: v_cvt_pk_bf16_f32 was tried (R8) and FAILED numerically (~RTZ bias).
__device__ __forceinline__ unsigned pk_rhu(float a, float b) {
  union { float f; unsigned u; } x, y; x.f = a; y.f = b;
  return ((x.u + 0x8000u) >> 16) | ((y.u + 0x8000u) & 0xFFFF0000u);
}

// ---------------------------------------------------------------------------
// Transpose weights to bf16 W^T (tiny): WqT/WkT[96][512], WvT[256][512],
// WxT[512][256].
// ---------------------------------------------------------------------------
__global__ __launch_bounds__(256) void transpose_w(
    const float* __restrict__ Wq, const float* __restrict__ Wk,
    const float* __restrict__ Wv, const float* __restrict__ Wx,
    unsigned short* __restrict__ wqT, unsigned short* __restrict__ wkT,
    unsigned short* __restrict__ wvT, unsigned short* __restrict__ wxT)
{
  int i = blockIdx.x * 256 + threadIdx.x;
  if (i < 49152) {
    const int n = i / 512, kk = i % 512;
    wqT[i] = f2bf(Wq[(size_t)kk * 96 + n]);
  } else if (i < 98304) {
    i -= 49152; const int n = i / 512, kk = i % 512;
    wkT[i] = f2bf(Wk[(size_t)kk * 96 + n]);
  } else if (i < 229376) {
    i -= 98304; const int n = i / 512, kk = i % 512;
    wvT[i] = f2bf(Wv[(size_t)kk * 256 + n]);
  } else if (i < 360448) {
    i -= 229376; const int n = i / 256, kk = i % 256;
    wxT[i] = f2bf(Wx[(size_t)kk * 512 + n]);
  }
}

// ---------------------------------------------------------------------------
// Fused QKV projection, LDS-free MFMA, fp32 A loaded directly (cast fused via
// round-half-up pack), pad/mask fill fused into epilogue. 512 blocks,
// XCD-swizzled.
// ys 0..2: q col-tile ys     -> q_bf (padded-head layout, * qscale)
// ys 3..5: k col-tile ys-3   -> k_bf (padded-head layout, mask in pad slot)
// ys 6..7: v, 4 col-tiles    -> vT_bf [b][256][2048] (swapped-operand MFMA)
// ---------------------------------------------------------------------------
__global__ __launch_bounds__(256) void proj_qkv(
    const float* __restrict__ query, const float* __restrict__ key_,
    const float* __restrict__ value, const int* __restrict__ mask,
    const unsigned short* __restrict__ wqT, const unsigned short* __restrict__ wkT,
    const unsigned short* __restrict__ wvT,
    const float* __restrict__ bq, const float* __restrict__ bk,
    const float* __restrict__ bv,
    unsigned short* __restrict__ q_bf, unsigned short* __restrict__ k_bf,
    unsigned short* __restrict__ vT_bf, float qscale)
{
  const int id = blockIdx.x;
  const int xcd = id & 7, j = id >> 3;
  const int bxl = j & 7, ys = j >> 3;
  const int bx = xcd * 8 + bxl;
  const int t = threadIdx.x, w = t >> 6, lane = t & 63;
  const int lo = lane & 31, hi = lane >> 5;
  const int r0 = bx * 128 + 32 * w;

  if (ys < 6) {
    const bool isq = (ys < 3);
    const float* A = isq ? query : key_;
    const unsigned short* BT = isq ? wqT : wkT;
    const float* bias = isq ? bq : bk;
    unsigned short* Cb = isq ? q_bf : k_bf;
    const float osc = isq ? qscale : 1.0f;
    const int c0 = (isq ? ys : ys - 3) * 32;

    const float* ap = A + (size_t)(r0 + lo) * 512 + hi * 8;
    const unsigned short* bp = BT + (size_t)(c0 + lo) * 512 + hi * 8;

    f32x16 acc;
#pragma unroll
    for (int r = 0; r < 16; ++r) acc[r] = 0.f;

    for (int k0 = 0; k0 < 512; k0 += 16) {
      const float4 a0 = *reinterpret_cast<const float4*>(ap + k0);
      const float4 a1 = *reinterpret_cast<const float4*>(ap + k0 + 4);
      union { bfrag8 fr; unsigned u[4]; } afu;
      afu.u[0] = pk_rhu(a0.x, a0.y); afu.u[1] = pk_rhu(a0.z, a0.w);
      afu.u[2] = pk_rhu(a1.x, a1.y); afu.u[3] = pk_rhu(a1.z, a1.w);
      const bfrag8 bf = *reinterpret_cast<const bfrag8*>(bp + k0);
      acc = __builtin_amdgcn_mfma_f32_32x32x16_bf16(afu.fr, bf, acc, 0, 0, 0);
    }

    const int c = c0 + lo;
    const int off = (c / 12) * 16 + (c % 12);
    const float bc = bias[c];
#pragma unroll
    for (int r = 0; r < 16; ++r) {
      const int grow = r0 + (r & 3) + 8 * (r >> 2) + 4 * hi;
      Cb[(size_t)grow * 128 + off] = f2bf((acc[r] + bc) * osc);
    }
    // fused pad fill: one lane per head per tile (c multiple of 12)
    if ((c % 12) == 0) {
      const int hh = c / 12;
#pragma unroll
      for (int r = 0; r < 16; ++r) {
        const int grow = r0 + (r & 3) + 8 * (r >> 2) + 4 * hi;
        ushort4 pv;
        pv.x = isq ? (unsigned short)0x3F80
                   : ((mask[grow] != 0) ? (unsigned short)0
                                        : (unsigned short)0xCE6E);
        pv.y = 0; pv.z = 0; pv.w = 0;
        *reinterpret_cast<ushort4*>(Cb + (size_t)grow * 128 + hh * 16 + 12) = pv;
      }
    }
  } else {
    const int ct0 = (ys - 6) * 128;
    const float* ap = value + (size_t)(r0 + lo) * 512 + hi * 8;
    const unsigned short* bp = wvT + (size_t)(ct0 + lo) * 512 + hi * 8;

    f32x16 acc[4];
#pragma unroll
    for (int tt = 0; tt < 4; ++tt)
#pragma unroll
      for (int r = 0; r < 16; ++r) acc[tt][r] = 0.f;

    for (int k0 = 0; k0 < 512; k0 += 16) {
      const float4 a0 = *reinterpret_cast<const float4*>(ap + k0);
      const float4 a1 = *reinterpret_cast<const float4*>(ap + k0 + 4);
      union { bfrag8 fr; unsigned u[4]; } afu;
      afu.u[0] = pk_rhu(a0.x, a0.y); afu.u[1] = pk_rhu(a0.z, a0.w);
      afu.u[2] = pk_rhu(a1.x, a1.y); afu.u[3] = pk_rhu(a1.z, a1.w);
#pragma unroll
      for (int tt = 0; tt < 4; ++tt) {
        const bfrag8 bf = *reinterpret_cast<const bfrag8*>(
            bp + (size_t)tt * 32 * 512 + k0);
        acc[tt] = __builtin_amdgcn_mfma_f32_32x32x16_bf16(bf, afu.fr, acc[tt], 0, 0, 0);
      }
    }

    const int s = r0 + lo;
    const int bb = s >> 11, sl = s & (S_LEN - 1);
#pragma unroll
    for (int tt = 0; tt < 4; ++tt) {
#pragma unroll
      for (int r = 0; r < 16; ++r) {
        const int c = ct0 + tt * 32 + (r & 3) + 8 * (r >> 2) + 4 * hi;
        vT_bf[((size_t)(bb * 256 + c)) * S_LEN + sl] = f2bf(acc[tt][r] + bv[c]);
      }
    }
  }
}

// ---------------------------------------------------------------------------
// MFMA attention: block = 32 q rows of one (b,h), 4 waves split the key dim;
// fragments direct from global bf16; XCD swizzle (4 bh per XCD); mask folded
// into pad dim 12. qscale includes log2(e) so softmax uses raw v_exp_f32.
// p stores batched 64-wide (256B contiguous runs per row) via per-wave
// p_lds[32][68]; PV A-fragment repack uses round-half-up pack (pk_rhu).
// ---------------------------------------------------------------------------
__global__ __launch_bounds__(256) void attn_mfma(
    const unsigned short* __restrict__ q_bf,
    const unsigned short* __restrict__ k_bf,
    const unsigned short* __restrict__ vT_bf,
    float* __restrict__ p_out, unsigned short* __restrict__ x_bf)
{
  const int id = blockIdx.x + blockIdx.y * 64;       // 0..2047
  const int xcd = id & 7, jj = id >> 3;
  const int bh = 4 * xcd + (jj >> 6);                // 4 bh per XCD
  const int q0 = (jj & 63) * 32;
  const int b = bh >> 3, h = bh & 7;
  const int t = threadIdx.x, w = t >> 6, lane = t & 63;
  const int lo = lane & 31, hi = lane >> 5;

  __shared__ float red_lds[4][32];
  __shared__ __align__(16) char smbuf[4 * 32 * 68 * 4];  // p[4][32][68] | xr[4][64][20]
  float (*p_lds)[32][68] = reinterpret_cast<float (*)[32][68]>(smbuf);
  float (*xr)[64][20]    = reinterpret_cast<float (*)[64][20]>(smbuf);

  const bfrag8 qf = *reinterpret_cast<const bfrag8*>(
      q_bf + (size_t)(b * S_LEN + q0 + lo) * 128 + h * 16 + hi * 8);
  const unsigned short* kbase = k_bf + (size_t)b * S_LEN * 128 + h * 16 + hi * 8;

  f32x16 zc;
#pragma unroll
  for (int r = 0; r < 16; ++r) zc[r] = 0.f;

  // ---------------- pass 1: row sums ----------------
  float sum = 0.f;
  for (int ch = w * 64; ch < S_LEN; ch += 256) {
#pragma unroll
    for (int T = 0; T < 2; ++T) {
      const bfrag8 kf = *reinterpret_cast<const bfrag8*>(
          kbase + (size_t)(ch + T * 32 + lo) * 128);
      const f32x16 sc = __builtin_amdgcn_mfma_f32_32x32x16_bf16(kf, qf, zc, 0, 0, 0);
#pragma unroll
      for (int r = 0; r < 16; ++r) sum += EXP2(sc[r]);
    }
  }
  sum += __shfl_xor(sum, 32);
  if (hi == 0) red_lds[w][lo] = sum;
  __syncthreads();
  const float inv = 1.0f /
      (red_lds[0][lo] + red_lds[1][lo] + red_lds[2][lo] + red_lds[3][lo]);

  // ---------------- pass 2: p write + PV ----------------
  f32x16 xacc;
#pragma unroll
  for (int r = 0; r < 16; ++r) xacc[r] = 0.f;

  const unsigned short* vbase = vT_bf + (size_t)(b * 256 + h * 32 + lo) * S_LEN;
  float* pg0 = p_out + (size_t)bh * S_LEN * S_LEN + (size_t)q0 * S_LEN;

  for (int ch = w * 64; ch < S_LEN; ch += 256) {
#pragma unroll
    for (int T = 0; T < 2; ++T) {
      const bfrag8 kf = *reinterpret_cast<const bfrag8*>(
          kbase + (size_t)(ch + T * 32 + lo) * 128);
      const f32x16 sc = __builtin_amdgcn_mfma_f32_32x32x16_bf16(kf, qf, zc, 0, 0, 0);

#pragma unroll
      for (int qd = 0; qd < 4; ++qd) {
        f32x4 ev;
        ev.x = EXP2(sc[qd * 4 + 0]) * inv;
        ev.y = EXP2(sc[qd * 4 + 1]) * inv;
        ev.z = EXP2(sc[qd * 4 + 2]) * inv;
        ev.w = EXP2(sc[qd * 4 + 3]) * inv;
        *reinterpret_cast<f32x4*>(&p_lds[w][lo][T * 32 + qd * 8 + hi * 4]) = ev;
      }

#pragma unroll
      for (int m = 0; m < 2; ++m) {
        const f32x4 pa = *reinterpret_cast<const f32x4*>(
            &p_lds[w][lo][T * 32 + m * 16 + hi * 8]);
        const f32x4 pb = *reinterpret_cast<const f32x4*>(
            &p_lds[w][lo][T * 32 + m * 16 + hi * 8 + 4]);
        union { bfrag8 fr; unsigned u[4]; } afu;
        afu.u[0] = pk_rhu(pa.x, pa.y); afu.u[1] = pk_rhu(pa.z, pa.w);
        afu.u[2] = pk_rhu(pb.x, pb.y); afu.u[3] = pk_rhu(pb.z, pb.w);
        const bfrag8 vf = *reinterpret_cast<const bfrag8*>(
            vbase + ch + T * 32 + m * 16 + hi * 8);
        xacc = __builtin_amdgcn_mfma_f32_32x32x16_bf16(afu.fr, vf, xacc, 0, 0, 0);
      }
    }

    // 64-wide (256B per row) nontemporal p stores: 4 rows x 64 keys / instr
    float* pg = pg0 + ch;
#pragma unroll
    for (int i = 0; i < 8; ++i) {
      const int row = i * 4 + (lane >> 4);
      const int k4  = (lane & 15) * 4;
      const f32x4 pv = *reinterpret_cast<const f32x4*>(&p_lds[w][row][k4]);
      __builtin_nontemporal_store(pv,
          reinterpret_cast<f32x4*>(pg + (size_t)row * S_LEN + k4));
    }
  }

  // ---------------- cross-wave X reduce + bf16 write ----------------
  __syncthreads();
#pragma unroll
  for (int r = 0; r < 16; r += 4) {
    f32x4 v4; v4.x = xacc[r]; v4.y = xacc[r + 1]; v4.z = xacc[r + 2]; v4.w = xacc[r + 3];
    *reinterpret_cast<f32x4*>(&xr[w][lane][r]) = v4;
  }
  __syncthreads();
  unsigned short* xw = x_bf + (size_t)(b * S_LEN + q0) * 256 + h * 32 + lo;
#pragma unroll
  for (int j = 0; j < 4; ++j) {
    const int rr = w * 4 + j;
    const float xs = xr[0][lane][rr] + xr[1][lane][rr]
                   + xr[2][lane][rr] + xr[3][lane][rr];
    const int row = j + 8 * w + 4 * hi;
    xw[(size_t)row * 256] = f2bf(xs);
  }
}

// ---------------------------------------------------------------------------
// Output projection: C[8192,512] = x_bf[8192,256] @ WxT^T + bx, fp32 out.
// 256 blocks, XCD-swizzled.
// ---------------------------------------------------------------------------
__global__ __launch_bounds__(256) void out_proj(
    const unsigned short* __restrict__ x_bf,
    const unsigned short* __restrict__ wxT,
    const float* __restrict__ bx, float* __restrict__ out)
{
  const int id = blockIdx.x;
  const int xcd = id & 7, j = id >> 3;
  const int bxl = j & 7, by = j >> 3;
  const int bx_ = xcd * 8 + bxl;
  const int t = threadIdx.x, w = t >> 6, lane = t & 63;
  const int lo = lane & 31, hi = lane >> 5;
  const int r0 = bx_ * 128 + 32 * w;
  const int c00 = by * 128;

  const unsigned short* ap = x_bf + (size_t)(r0 + lo) * 256 + hi * 8;
  const unsigned short* bp = wxT + (size_t)(c00 + lo) * 256 + hi * 8;

  f32x16 acc[4];
#pragma unroll
  for (int tt = 0; tt < 4; ++tt)
#pragma unroll
    for (int r = 0; r < 16; ++r) acc[tt][r] = 0.f;

  for (int k0 = 0; k0 < 256; k0 += 16) {
    const bfrag8 af = *reinterpret_cast<const bfrag8*>(ap + k0);
#pragma unroll
    for (int tt = 0; tt < 4; ++tt) {
      const bfrag8 bf = *reinterpret_cast<const bfrag8*>(
          bp + (size_t)tt * 32 * 256 + k0);
      acc[tt] = __builtin_amdgcn_mfma_f32_32x32x16_bf16(af, bf, acc[tt], 0, 0, 0);
    }
  }

#pragma unroll
  for (int tt = 0; tt < 4; ++tt) {
    const int c = c00 + tt * 32 + lo;
    const float bc = bx[c];
#pragma unroll
    for (int r = 0; r < 16; ++r) {
      const int grow = r0 + (r & 3) + 8 * (r >> 2) + 4 * hi;
      out[(size_t)grow * 512 + c] = acc[tt][r] + bc;
    }
  }
}

// ---------------------------------------------------------------------------
extern "C" void kernel_launch(void* const* d_in, const int* in_sizes, int n_in,
                              void* d_out, int out_size, void* d_ws, size_t ws_size,
                              hipStream_t stream) {
  const float* query = (const float*)d_in[0];
  const float* key_  = (const float*)d_in[1];
  const float* value = (const float*)d_in[2];
  const int*   mask  = (const int*)d_in[3];
  const float* Wq = (const float*)d_in[4];
  const float* bq = (const float*)d_in[5];
  const float* Wk = (const float*)d_in[6];
  const float* bk = (const float*)d_in[7];
  const float* Wv = (const float*)d_in[8];
  const float* bv = (const float*)d_in[9];
  const float* Wx = (const float*)d_in[10];
  const float* bx = (const float*)d_in[11];

  const int M = NB * S_LEN;                  // 8192
  float* out_x = (float*)d_out;              // [4,2048,512]
  float* out_p = out_x + (size_t)M * 512;    // [4,8,2048,2048]

  unsigned short* wqT  = (unsigned short*)d_ws;             // 96*512
  unsigned short* wkT  = wqT + 49152;                       // 96*512
  unsigned short* wvT  = wkT + 49152;                       // 256*512
  unsigned short* wxT  = wvT + 131072;                      // 512*256
  unsigned short* q_bf = wxT + 131072;                      // 8192*128
  unsigned short* k_bf = q_bf + (size_t)M * 128;            // 8192*128
  unsigned short* vT_bf = k_bf + (size_t)M * 128;           // 4*256*2048
  unsigned short* x_bf = vT_bf + (size_t)NB * 256 * S_LEN;  // 8192*256

  // 1/sqrt(12) * log2(e): scores come out of the MFMA in log2 units, so
  // softmax needs only raw v_exp_f32 (exp2), no per-element multiply.
  const float qscale = 1.4426950408889634f / sqrtf(12.0f);

  transpose_w<<<1408, 256, 0, stream>>>(Wq, Wk, Wv, Wx, wqT, wkT, wvT, wxT);

  proj_qkv<<<512, 256, 0, stream>>>(
      query, key_, value, mask, wqT, wkT, wvT, bq, bk, bv,
      q_bf, k_bf, vT_bf, qscale);

  attn_mfma<<<dim3(S_LEN / 32, NB * NH), 256, 0, stream>>>(
      q_bf, k_bf, vT_bf, out_p, x_bf);

  out_proj<<<256, 256, 0, stream>>>(x_bf, wxT, bx, out_x);
}

// Round 12
// 167.763 us; speedup vs baseline: 1.0405x; 1.0405x over previous
//
#include <hip/hip_runtime.h>
#include <math.h>

#define S_LEN 2048
#define NB 4
#define NH 8

typedef short bfrag8 __attribute__((ext_vector_type(8)));
typedef float f32x16 __attribute__((ext_vector_type(16)));
typedef float f32x4 __attribute__((ext_vector_type(4)));

#if __has_builtin(__builtin_amdgcn_exp2f)
#define EXP2(x) __builtin_amdgcn_exp2f(x)
#else
#define EXP2(x) exp2f(x)
#endif

__device__ __forceinline__ unsigned short f2bf(float x) {
  union { float f; unsigned u; } v; v.f = x;
  unsigned r = v.u + 0x7FFFu + ((v.u >> 16) & 1u);
  return (unsigned short)(r >> 16);
}

// ---------------------------------------------------------------------------
// Transpose weights to bf16 W^T (tiny): WqT/WkT[96][512], WvT[256][512],
// WxT[512][256].
// ---------------------------------------------------------------------------
__global__ __launch_bounds__(256) void transpose_w(
    const float* __restrict__ Wq, const float* __restrict__ Wk,
    const float* __restrict__ Wv, const float* __restrict__ Wx,
    unsigned short* __restrict__ wqT, unsigned short* __restrict__ wkT,
    unsigned short* __restrict__ wvT, unsigned short* __restrict__ wxT)
{
  int i = blockIdx.x * 256 + threadIdx.x;
  if (i < 49152) {
    const int n = i / 512, kk = i % 512;
    wqT[i] = f2bf(Wq[(size_t)kk * 96 + n]);
  } else if (i < 98304) {
    i -= 49152; const int n = i / 512, kk = i % 512;
    wkT[i] = f2bf(Wk[(size_t)kk * 96 + n]);
  } else if (i < 229376) {
    i -= 98304; const int n = i / 512, kk = i % 512;
    wvT[i] = f2bf(Wv[(size_t)kk * 256 + n]);
  } else if (i < 360448) {
    i -= 229376; const int n = i / 256, kk = i % 256;
    wxT[i] = f2bf(Wx[(size_t)kk * 512 + n]);
  }
}

// ---------------------------------------------------------------------------
// Fused QKV projection (verified R10 structure): 512 blocks, XCD-swizzled.
// ys 0..2: q col-tile ys     -> q_bf (padded-head layout, * qscale)
// ys 3..5: k col-tile ys-3   -> k_bf (padded-head layout, mask in pad slot)
// ys 6..7: v, 4 col-tiles    -> vT_bf [b][256][2048] (swapped-operand MFMA)
// ---------------------------------------------------------------------------
__global__ __launch_bounds__(256) void proj_qkv(
    const float* __restrict__ query, const float* __restrict__ key_,
    const float* __restrict__ value, const int* __restrict__ mask,
    const unsigned short* __restrict__ wqT, const unsigned short* __restrict__ wkT,
    const unsigned short* __restrict__ wvT,
    const float* __restrict__ bq, const float* __restrict__ bk,
    const float* __restrict__ bv,
    unsigned short* __restrict__ q_bf, unsigned short* __restrict__ k_bf,
    unsigned short* __restrict__ vT_bf, float qscale)
{
  const int id = blockIdx.x;
  const int xcd = id & 7, j = id >> 3;
  const int bxl = j & 7, ys = j >> 3;
  const int bx = xcd * 8 + bxl;
  const int t = threadIdx.x, w = t >> 6, lane = t & 63;
  const int lo = lane & 31, hi = lane >> 5;
  const int r0 = bx * 128 + 32 * w;

  if (ys < 6) {
    const bool isq = (ys < 3);
    const float* A = isq ? query : key_;
    const unsigned short* BT = isq ? wqT : wkT;
    const float* bias = isq ? bq : bk;
    unsigned short* Cb = isq ? q_bf : k_bf;
    const float osc = isq ? qscale : 1.0f;
    const int c0 = (isq ? ys : ys - 3) * 32;

    const float* ap = A + (size_t)(r0 + lo) * 512 + hi * 8;
    const unsigned short* bp = BT + (size_t)(c0 + lo) * 512 + hi * 8;

    f32x16 acc;
#pragma unroll
    for (int r = 0; r < 16; ++r) acc[r] = 0.f;

    for (int k0 = 0; k0 < 512; k0 += 16) {
      const float4 a0 = *reinterpret_cast<const float4*>(ap + k0);
      const float4 a1 = *reinterpret_cast<const float4*>(ap + k0 + 4);
      bfrag8 af;
      af[0] = (short)f2bf(a0.x); af[1] = (short)f2bf(a0.y);
      af[2] = (short)f2bf(a0.z); af[3] = (short)f2bf(a0.w);
      af[4] = (short)f2bf(a1.x); af[5] = (short)f2bf(a1.y);
      af[6] = (short)f2bf(a1.z); af[7] = (short)f2bf(a1.w);
      const bfrag8 bf = *reinterpret_cast<const bfrag8*>(bp + k0);
      acc = __builtin_amdgcn_mfma_f32_32x32x16_bf16(af, bf, acc, 0, 0, 0);
    }

    const int c = c0 + lo;
    const int off = (c / 12) * 16 + (c % 12);
    const float bc = bias[c];
#pragma unroll
    for (int r = 0; r < 16; ++r) {
      const int grow = r0 + (r & 3) + 8 * (r >> 2) + 4 * hi;
      Cb[(size_t)grow * 128 + off] = f2bf((acc[r] + bc) * osc);
    }
    // fused pad fill: one lane per head per tile (c multiple of 12)
    if ((c % 12) == 0) {
      const int hh = c / 12;
#pragma unroll
      for (int r = 0; r < 16; ++r) {
        const int grow = r0 + (r & 3) + 8 * (r >> 2) + 4 * hi;
        ushort4 pv;
        pv.x = isq ? (unsigned short)0x3F80
                   : ((mask[grow] != 0) ? (unsigned short)0
                                        : (unsigned short)0xCE6E);
        pv.y = 0; pv.z = 0; pv.w = 0;
        *reinterpret_cast<ushort4*>(Cb + (size_t)grow * 128 + hh * 16 + 12) = pv;
      }
    }
  } else {
    const int ct0 = (ys - 6) * 128;
    const float* ap = value + (size_t)(r0 + lo) * 512 + hi * 8;
    const unsigned short* bp = wvT + (size_t)(ct0 + lo) * 512 + hi * 8;

    f32x16 acc[4];
#pragma unroll
    for (int tt = 0; tt < 4; ++tt)
#pragma unroll
      for (int r = 0; r < 16; ++r) acc[tt][r] = 0.f;

    for (int k0 = 0; k0 < 512; k0 += 16) {
      const float4 a0 = *reinterpret_cast<const float4*>(ap + k0);
      const float4 a1 = *reinterpret_cast<const float4*>(ap + k0 + 4);
      bfrag8 af;
      af[0] = (short)f2bf(a0.x); af[1] = (short)f2bf(a0.y);
      af[2] = (short)f2bf(a0.z); af[3] = (short)f2bf(a0.w);
      af[4] = (short)f2bf(a1.x); af[5] = (short)f2bf(a1.y);
      af[6] = (short)f2bf(a1.z); af[7] = (short)f2bf(a1.w);
#pragma unroll
      for (int tt = 0; tt < 4; ++tt) {
        const bfrag8 bf = *reinterpret_cast<const bfrag8*>(
            bp + (size_t)tt * 32 * 512 + k0);
        acc[tt] = __builtin_amdgcn_mfma_f32_32x32x16_bf16(bf, af, acc[tt], 0, 0, 0);
      }
    }

    const int s = r0 + lo;
    const int bb = s >> 11, sl = s & (S_LEN - 1);
#pragma unroll
    for (int tt = 0; tt < 4; ++tt) {
#pragma unroll
      for (int r = 0; r < 16; ++r) {
        const int c = ct0 + tt * 32 + (r & 3) + 8 * (r >> 2) + 4 * hi;
        vT_bf[((size_t)(bb * 256 + c)) * S_LEN + sl] = f2bf(acc[tt][r] + bv[c]);
      }
    }
  }
}

// ---------------------------------------------------------------------------
// MFMA attention (R10 base + ISOLATED cross-chunk K-fragment prefetch).
// Block = 32 q rows of one (b,h), 4 waves split the key dim; fragments direct
// from global bf16; XCD swizzle (4 bh per XCD); mask folded into pad dim 12;
// qscale includes log2(e) so softmax is raw v_exp_f32; NT 64-wide p stores.
// Prefetch mechanism: next chunk's two K fragments are issued before this
// chunk's compute, hiding ~200-350cyc L2 latency at ~4 waves/SIMD occupancy.
// ---------------------------------------------------------------------------
__global__ __launch_bounds__(256) void attn_mfma(
    const unsigned short* __restrict__ q_bf,
    const unsigned short* __restrict__ k_bf,
    const unsigned short* __restrict__ vT_bf,
    float* __restrict__ p_out, unsigned short* __restrict__ x_bf)
{
  const int id = blockIdx.x + blockIdx.y * 64;       // 0..2047
  const int xcd = id & 7, jj = id >> 3;
  const int bh = 4 * xcd + (jj >> 6);                // 4 bh per XCD
  const int q0 = (jj & 63) * 32;
  const int b = bh >> 3, h = bh & 7;
  const int t = threadIdx.x, w = t >> 6, lane = t & 63;
  const int lo = lane & 31, hi = lane >> 5;

  __shared__ float red_lds[4][32];
  __shared__ __align__(16) char smbuf[4 * 32 * 68 * 4];  // p[4][32][68] | xr[4][64][20]
  float (*p_lds)[32][68] = reinterpret_cast<float (*)[32][68]>(smbuf);
  float (*xr)[64][20]    = reinterpret_cast<float (*)[64][20]>(smbuf);

  const bfrag8 qf = *reinterpret_cast<const bfrag8*>(
      q_bf + (size_t)(b * S_LEN + q0 + lo) * 128 + h * 16 + hi * 8);
  const unsigned short* kbase = k_bf + (size_t)b * S_LEN * 128 + h * 16 + hi * 8;

  f32x16 zc;
#pragma unroll
  for (int r = 0; r < 16; ++r) zc[r] = 0.f;

  // ---------------- pass 1: row sums (K prefetched across chunks) ---------
  float sum = 0.f;
  {
    bfrag8 k0f = *reinterpret_cast<const bfrag8*>(
        kbase + (size_t)(w * 64 + lo) * 128);
    bfrag8 k1f = *reinterpret_cast<const bfrag8*>(
        kbase + (size_t)(w * 64 + 32 + lo) * 128);
    for (int ch = w * 64; ch < S_LEN; ch += 256) {
      const int nch = (ch + 256 < S_LEN) ? ch + 256 : ch;
      const bfrag8 n0 = *reinterpret_cast<const bfrag8*>(
          kbase + (size_t)(nch + lo) * 128);
      const bfrag8 n1 = *reinterpret_cast<const bfrag8*>(
          kbase + (size_t)(nch + 32 + lo) * 128);
      const f32x16 s0 = __builtin_amdgcn_mfma_f32_32x32x16_bf16(k0f, qf, zc, 0, 0, 0);
#pragma unroll
      for (int r = 0; r < 16; ++r) sum += EXP2(s0[r]);
      const f32x16 s1 = __builtin_amdgcn_mfma_f32_32x32x16_bf16(k1f, qf, zc, 0, 0, 0);
#pragma unroll
      for (int r = 0; r < 16; ++r) sum += EXP2(s1[r]);
      k0f = n0; k1f = n1;
    }
  }
  sum += __shfl_xor(sum, 32);
  if (hi == 0) red_lds[w][lo] = sum;
  __syncthreads();
  const float inv = 1.0f /
      (red_lds[0][lo] + red_lds[1][lo] + red_lds[2][lo] + red_lds[3][lo]);

  // ---------------- pass 2: p write + PV (K prefetched) ----------------
  f32x16 xacc;
#pragma unroll
  for (int r = 0; r < 16; ++r) xacc[r] = 0.f;

  const unsigned short* vbase = vT_bf + (size_t)(b * 256 + h * 32 + lo) * S_LEN;
  float* pg0 = p_out + (size_t)bh * S_LEN * S_LEN + (size_t)q0 * S_LEN;

  bfrag8 k0f = *reinterpret_cast<const bfrag8*>(
      kbase + (size_t)(w * 64 + lo) * 128);
  bfrag8 k1f = *reinterpret_cast<const bfrag8*>(
      kbase + (size_t)(w * 64 + 32 + lo) * 128);

  for (int ch = w * 64; ch < S_LEN; ch += 256) {
    const int nch = (ch + 256 < S_LEN) ? ch + 256 : ch;
    const bfrag8 n0 = *reinterpret_cast<const bfrag8*>(
        kbase + (size_t)(nch + lo) * 128);
    const bfrag8 n1 = *reinterpret_cast<const bfrag8*>(
        kbase + (size_t)(nch + 32 + lo) * 128);

#pragma unroll
    for (int T = 0; T < 2; ++T) {
      const f32x16 sc = __builtin_amdgcn_mfma_f32_32x32x16_bf16(
          T ? k1f : k0f, qf, zc, 0, 0, 0);

#pragma unroll
      for (int qd = 0; qd < 4; ++qd) {
        f32x4 ev;
        ev.x = EXP2(sc[qd * 4 + 0]) * inv;
        ev.y = EXP2(sc[qd * 4 + 1]) * inv;
        ev.z = EXP2(sc[qd * 4 + 2]) * inv;
        ev.w = EXP2(sc[qd * 4 + 3]) * inv;
        *reinterpret_cast<f32x4*>(&p_lds[w][lo][T * 32 + qd * 8 + hi * 4]) = ev;
      }

#pragma unroll
      for (int m = 0; m < 2; ++m) {
        const f32x4 pa = *reinterpret_cast<const f32x4*>(
            &p_lds[w][lo][T * 32 + m * 16 + hi * 8]);
        const f32x4 pb = *reinterpret_cast<const f32x4*>(
            &p_lds[w][lo][T * 32 + m * 16 + hi * 8 + 4]);
        bfrag8 af;
        af[0] = (short)f2bf(pa.x); af[1] = (short)f2bf(pa.y);
        af[2] = (short)f2bf(pa.z); af[3] = (short)f2bf(pa.w);
        af[4] = (short)f2bf(pb.x); af[5] = (short)f2bf(pb.y);
        af[6] = (short)f2bf(pb.z); af[7] = (short)f2bf(pb.w);
        const bfrag8 vf = *reinterpret_cast<const bfrag8*>(
            vbase + ch + T * 32 + m * 16 + hi * 8);
        xacc = __builtin_amdgcn_mfma_f32_32x32x16_bf16(af, vf, xacc, 0, 0, 0);
      }
    }

    // 64-wide (256B per row) nontemporal p stores: 4 rows x 64 keys / instr
    float* pg = pg0 + ch;
#pragma unroll
    for (int i = 0; i < 8; ++i) {
      const int row = i * 4 + (lane >> 4);
      const int k4  = (lane & 15) * 4;
      const f32x4 pv = *reinterpret_cast<const f32x4*>(&p_lds[w][row][k4]);
      __builtin_nontemporal_store(pv,
          reinterpret_cast<f32x4*>(pg + (size_t)row * S_LEN + k4));
    }
    k0f = n0; k1f = n1;
  }

  // ---------------- cross-wave X reduce + bf16 write ----------------
  __syncthreads();
#pragma unroll
  for (int r = 0; r < 16; r += 4) {
    f32x4 v4; v4.x = xacc[r]; v4.y = xacc[r + 1]; v4.z = xacc[r + 2]; v4.w = xacc[r + 3];
    *reinterpret_cast<f32x4*>(&xr[w][lane][r]) = v4;
  }
  __syncthreads();
  unsigned short* xw = x_bf + (size_t)(b * S_LEN + q0) * 256 + h * 32 + lo;
#pragma unroll
  for (int j = 0; j < 4; ++j) {
    const int rr = w * 4 + j;
    const float xs = xr[0][lane][rr] + xr[1][lane][rr]
                   + xr[2][lane][rr] + xr[3][lane][rr];
    const int row = j + 8 * w + 4 * hi;
    xw[(size_t)row * 256] = f2bf(xs);
  }
}

// ---------------------------------------------------------------------------
// Output projection: C[8192,512] = x_bf[8192,256] @ WxT^T + bx, fp32 out.
// 256 blocks, XCD-swizzled.
// ---------------------------------------------------------------------------
__global__ __launch_bounds__(256) void out_proj(
    const unsigned short* __restrict__ x_bf,
    const unsigned short* __restrict__ wxT,
    const float* __restrict__ bx, float* __restrict__ out)
{
  const int id = blockIdx.x;
  const int xcd = id & 7, j = id >> 3;
  const int bxl = j & 7, by = j >> 3;
  const int bx_ = xcd * 8 + bxl;
  const int t = threadIdx.x, w = t >> 6, lane = t & 63;
  const int lo = lane & 31, hi = lane >> 5;
  const int r0 = bx_ * 128 + 32 * w;
  const int c00 = by * 128;

  const unsigned short* ap = x_bf + (size_t)(r0 + lo) * 256 + hi * 8;
  const unsigned short* bp = wxT + (size_t)(c00 + lo) * 256 + hi * 8;

  f32x16 acc[4];
#pragma unroll
  for (int tt = 0; tt < 4; ++tt)
#pragma unroll
    for (int r = 0; r < 16; ++r) acc[tt][r] = 0.f;

  for (int k0 = 0; k0 < 256; k0 += 16) {
    const bfrag8 af = *reinterpret_cast<const bfrag8*>(ap + k0);
#pragma unroll
    for (int tt = 0; tt < 4; ++tt) {
      const bfrag8 bf = *reinterpret_cast<const bfrag8*>(
          bp + (size_t)tt * 32 * 256 + k0);
      acc[tt] = __builtin_amdgcn_mfma_f32_32x32x16_bf16(af, bf, acc[tt], 0, 0, 0);
    }
  }

#pragma unroll
  for (int tt = 0; tt < 4; ++tt) {
    const int c = c00 + tt * 32 + lo;
    const float bc = bx[c];
#pragma unroll
    for (int r = 0; r < 16; ++r) {
      const int grow = r0 + (r & 3) + 8 * (r >> 2) + 4 * hi;
      out[(size_t)grow * 512 + c] = acc[tt][r] + bc;
    }
  }
}

// ---------------------------------------------------------------------------
extern "C" void kernel_launch(void* const* d_in, const int* in_sizes, int n_in,
                              void* d_out, int out_size, void* d_ws, size_t ws_size,
                              hipStream_t stream) {
  const float* query = (const float*)d_in[0];
  const float* key_  = (const float*)d_in[1];
  const float* value = (const float*)d_in[2];
  const int*   mask  = (const int*)d_in[3];
  const float* Wq = (const float*)d_in[4];
  const float* bq = (const float*)d_in[5];
  const float* Wk = (const float*)d_in[6];
  const float* bk = (const float*)d_in[7];
  const float* Wv = (const float*)d_in[8];
  const float* bv = (const float*)d_in[9];
  const float* Wx = (const float*)d_in[10];
  const float* bx = (const float*)d_in[11];

  const int M = NB * S_LEN;                  // 8192
  float* out_x = (float*)d_out;              // [4,2048,512]
  float* out_p = out_x + (size_t)M * 512;    // [4,8,2048,2048]

  unsigned short* wqT  = (unsigned short*)d_ws;             // 96*512
  unsigned short* wkT  = wqT + 49152;                       // 96*512
  unsigned short* wvT  = wkT + 49152;                       // 256*512
  unsigned short* wxT  = wvT + 131072;                      // 512*256
  unsigned short* q_bf = wxT + 131072;                      // 8192*128
  unsigned short* k_bf = q_bf + (size_t)M * 128;            // 8192*128
  unsigned short* vT_bf = k_bf + (size_t)M * 128;           // 4*256*2048
  unsigned short* x_bf = vT_bf + (size_t)NB * 256 * S_LEN;  // 8192*256

  // 1/sqrt(12) * log2(e): scores come out of the MFMA in log2 units, so
  // softmax needs only raw v_exp_f32 (exp2), no per-element multiply.
  const float qscale = 1.4426950408889634f / sqrtf(12.0f);

  transpose_w<<<1408, 256, 0, stream>>>(Wq, Wk, Wv, Wx, wqT, wkT, wvT, wxT);

  proj_qkv<<<512, 256, 0, stream>>>(
      query, key_, value, mask, wqT, wkT, wvT, bq, bk, bv,
      q_bf, k_bf, vT_bf, qscale);

  attn_mfma<<<dim3(S_LEN / 32, NB * NH), 256, 0, stream>>>(
      q_bf, k_bf, vT_bf, out_p, x_bf);

  out_proj<<<256, 256, 0, stream>>>(x_bf, wxT, bx, out_x);
}